// Round 2
// baseline (16801.439 us; speedup 1.0000x reference)
//
#include <hip/hip_runtime.h>
#include <hip/hip_bf16.h>
#include <math.h>

#define DD 384
#define NBATCH 64
#define NSEQ 721
#define NROWS (NBATCH*NSEQ)   // 46144
#define NLAYER 4

// ---------------------------------------------------------------- build x
__global__ void build_x_kernel(const float* __restrict__ search,
                               const float* __restrict__ target,
                               const float* __restrict__ cls,
                               const float* __restrict__ spos,
                               const float* __restrict__ tpos,
                               float* __restrict__ x) {
    int idx = blockIdx.x * blockDim.x + threadIdx.x;   // float4 index
    const int D4 = DD / 4;
    int total = NROWS * D4;
    if (idx >= total) return;
    int d4  = idx % D4;
    int row = idx / D4;
    int b = row / NSEQ;
    int n = row % NSEQ;
    float4 val;
    if (n == 0) {
        val = ((const float4*)cls)[d4];
    } else if (n <= 576) {
        int i = n - 1;
        float4 s = ((const float4*)search)[(size_t)(b*576 + i)*D4 + d4];
        float4 p = ((const float4*)spos)[(size_t)i*D4 + d4];
        val = make_float4(s.x+p.x, s.y+p.y, s.z+p.z, s.w+p.w);
    } else {
        int i = n - 577;
        float4 s = ((const float4*)target)[(size_t)(b*144 + i)*D4 + d4];
        float4 p = ((const float4*)tpos)[(size_t)i*D4 + d4];
        val = make_float4(s.x+p.x, s.y+p.y, s.z+p.z, s.w+p.w);
    }
    ((float4*)x)[idx] = val;
}

// ---------------------------------------------------------------- LN stats
// one wave per row; writes mu, rstd (2 floats per row)
__global__ __launch_bounds__(256) void ln_stats_kernel(const float* __restrict__ x,
                                                       float* __restrict__ stats,
                                                       int M) {
    int wave = threadIdx.x >> 6;
    int lane = threadIdx.x & 63;
    int row = blockIdx.x * 4 + wave;
    if (row >= M) return;
    const float* xr = x + (size_t)row * DD;
    float v[6];
    float s = 0.f;
    #pragma unroll
    for (int i = 0; i < 6; i++) { v[i] = xr[lane + 64*i]; s += v[i]; }
    #pragma unroll
    for (int m = 1; m < 64; m <<= 1) s += __shfl_xor(s, m);
    float mu = s * (1.f/DD);
    float vs = 0.f;
    #pragma unroll
    for (int i = 0; i < 6; i++) { float d = v[i]-mu; vs += d*d; }
    #pragma unroll
    for (int m = 1; m < 64; m <<= 1) vs += __shfl_xor(vs, m);
    float rstd = rsqrtf(vs * (1.f/DD) + 1e-5f);
    if (lane == 0) { stats[row*2] = mu; stats[row*2+1] = rstd; }
}

// ---------------------------------------------------------------- f32 GEMM
// C[M,N] = f(op(A)[M,K] @ W[K,N] + bias)
//   LNA:  op(A)[m][k] = (A[m][k]-mu_m)*rstd_m*g[k]+b[k]
//   MODE 0: none, 1: exact gelu, 2: += res
// 128x128 tile, BK=16, 256 threads, 8x8 microtile
template<int MODE, bool LNA>
__global__ __launch_bounds__(256) void gemm_f32(const float* __restrict__ A,
                                                const float* __restrict__ stats,
                                                const float* __restrict__ lng,
                                                const float* __restrict__ lnb,
                                                const float* __restrict__ W,
                                                const float* __restrict__ bias,
                                                const float* __restrict__ res,
                                                float* __restrict__ C,
                                                int M, int N, int K) {
    __shared__ float As[16][132];
    __shared__ float Ws[16][132];
    int m0 = blockIdx.y * 128;
    int n0 = blockIdx.x * 128;
    int t  = threadIdx.x;
    int tm = t & 15, tn = t >> 4;
    float acc[8][8];
    #pragma unroll
    for (int i = 0; i < 8; i++)
        #pragma unroll
        for (int j = 0; j < 8; j++) acc[i][j] = 0.f;

    for (int k0 = 0; k0 < K; k0 += 16) {
        __syncthreads();
        // A tile 128x16 -> transposed As[k][m]
        #pragma unroll
        for (int s = 0; s < 2; s++) {
            int i = t + s*256;
            int row = i >> 2;          // 0..127
            int k4  = i & 3;           // float4 within 16-k row
            int gr = m0 + row;
            float4 a = make_float4(0,0,0,0);
            if (gr < M) {
                a = *(const float4*)(A + (size_t)gr*K + k0 + k4*4);
                if (LNA) {
                    float mu = stats[gr*2], rstd = stats[gr*2+1];
                    float4 gg = *(const float4*)(lng + k0 + k4*4);
                    float4 bb = *(const float4*)(lnb + k0 + k4*4);
                    a.x = (a.x-mu)*rstd*gg.x + bb.x;
                    a.y = (a.y-mu)*rstd*gg.y + bb.y;
                    a.z = (a.z-mu)*rstd*gg.z + bb.z;
                    a.w = (a.w-mu)*rstd*gg.w + bb.w;
                }
            }
            As[k4*4+0][row] = a.x; As[k4*4+1][row] = a.y;
            As[k4*4+2][row] = a.z; As[k4*4+3][row] = a.w;
        }
        // W tile 16x128
        #pragma unroll
        for (int s = 0; s < 2; s++) {
            int i = t + s*256;
            int kk = i >> 5;           // 0..15
            int n4 = i & 31;
            float4 w = *(const float4*)(W + (size_t)(k0+kk)*N + n0 + n4*4);
            *(float4*)&Ws[kk][n4*4] = w;
        }
        __syncthreads();
        #pragma unroll
        for (int kk = 0; kk < 16; kk++) {
            float4 a0 = *(const float4*)&As[kk][tm*4];
            float4 a1 = *(const float4*)&As[kk][64 + tm*4];
            float4 w0 = *(const float4*)&Ws[kk][tn*4];
            float4 w1 = *(const float4*)&Ws[kk][64 + tn*4];
            float am[8] = {a0.x,a0.y,a0.z,a0.w,a1.x,a1.y,a1.z,a1.w};
            float wn[8] = {w0.x,w0.y,w0.z,w0.w,w1.x,w1.y,w1.z,w1.w};
            #pragma unroll
            for (int mi = 0; mi < 8; mi++)
                #pragma unroll
                for (int ni = 0; ni < 8; ni++)
                    acc[mi][ni] = fmaf(am[mi], wn[ni], acc[mi][ni]);
        }
    }
    // epilogue
    #pragma unroll
    for (int mi = 0; mi < 8; mi++) {
        int row = m0 + ((mi & 4) << 4) + tm*4 + (mi & 3);
        if (row >= M) continue;
        #pragma unroll
        for (int nh = 0; nh < 2; nh++) {
            int col = n0 + nh*64 + tn*4;
            float r[4];
            #pragma unroll
            for (int ni = 0; ni < 4; ni++) {
                float vv = acc[mi][nh*4+ni] + bias[col+ni];
                if (MODE == 1) vv = 0.5f*vv*(1.f + erff(vv*0.70710678118654752f));
                r[ni] = vv;
            }
            if (MODE == 2) {
                float4 rv = *(const float4*)(res + (size_t)row*N + col);
                r[0]+=rv.x; r[1]+=rv.y; r[2]+=rv.z; r[3]+=rv.w;
            }
            float4 o = make_float4(r[0],r[1],r[2],r[3]);
            *(float4*)(C + (size_t)row*N + col) = o;
        }
    }
}

// ---------------------------------------------------------------- attention
// block = (i-tile of 16 q rows, batch-in-chunk). 256 threads: (r=t>>4, c=t&15)
// out[r][d] owned as d = c + 16*u, u=0..23. flash-style over j-tiles of 64.
__global__ __launch_bounds__(256) void attn_kernel(const float* __restrict__ q,
                                                   const float* __restrict__ k,
                                                   const float* __restrict__ v,
                                                   float* __restrict__ x) {
    __shared__ float qs[16][DD];
    __shared__ float ks[64][68];   // transposed chunk [d_local][j]
    __shared__ float vs[64][68];   // [j][d_local]
    __shared__ float ps[16][68];
    int b  = blockIdx.y;
    int i0 = blockIdx.x * 16;
    int t  = threadIdx.x;
    int r = t >> 4, c = t & 15;
    const float* qb = q + (size_t)b*NSEQ*DD;
    const float* kb = k + (size_t)b*NSEQ*DD;
    const float* vb = v + (size_t)b*NSEQ*DD;

    {   // load q tile (zero-fill invalid rows)
        int row = i0 + r;
        #pragma unroll
        for (int s = 0; s < 6; s++) {
            int d4 = c + 16*s;
            float4 qv = (row < NSEQ) ? *(const float4*)(qb + (size_t)row*DD + d4*4)
                                     : make_float4(0,0,0,0);
            *(float4*)&qs[r][d4*4] = qv;
        }
    }
    float out[24];
    #pragma unroll
    for (int u = 0; u < 24; u++) out[u] = 0.f;
    float mrow = -1e30f, lrow = 0.f;
    const float scale = 0.05103103630798287f;   // 384^-0.5

    for (int j0 = 0; j0 < NSEQ; j0 += 64) {
        int jmax = min(64, NSEQ - j0);
        float s0=0.f, s1=0.f, s2=0.f, s3=0.f;
        for (int d0 = 0; d0 < DD; d0 += 64) {
            __syncthreads();
            #pragma unroll
            for (int s = 0; s < 4; s++) {
                int i = t + s*256;
                int j = i >> 4, d4 = i & 15;
                float4 kv = (j < jmax) ? *(const float4*)(kb + (size_t)(j0+j)*DD + d0 + d4*4)
                                       : make_float4(0,0,0,0);
                ks[d4*4+0][j] = kv.x; ks[d4*4+1][j] = kv.y;
                ks[d4*4+2][j] = kv.z; ks[d4*4+3][j] = kv.w;
            }
            __syncthreads();
            #pragma unroll
            for (int dl = 0; dl < 64; dl++) {
                float qv = qs[r][d0+dl];
                float4 k4 = *(const float4*)&ks[dl][c*4];
                s0 = fmaf(qv, k4.x, s0); s1 = fmaf(qv, k4.y, s1);
                s2 = fmaf(qv, k4.z, s2); s3 = fmaf(qv, k4.w, s3);
            }
        }
        s0 *= scale; s1 *= scale; s2 *= scale; s3 *= scale;
        int jbase = j0 + c*4;
        if (jbase+0 >= NSEQ) s0 = -1e30f;
        if (jbase+1 >= NSEQ) s1 = -1e30f;
        if (jbase+2 >= NSEQ) s2 = -1e30f;
        if (jbase+3 >= NSEQ) s3 = -1e30f;
        float tmax = fmaxf(fmaxf(s0,s1), fmaxf(s2,s3));
        #pragma unroll
        for (int mm = 1; mm < 16; mm <<= 1) tmax = fmaxf(tmax, __shfl_xor(tmax, mm));
        float mnew = fmaxf(mrow, tmax);
        float corr = __expf(mrow - mnew);
        float p0 = __expf(s0 - mnew), p1 = __expf(s1 - mnew);
        float p2 = __expf(s2 - mnew), p3 = __expf(s3 - mnew);
        float psum = p0+p1+p2+p3;
        #pragma unroll
        for (int mm = 1; mm < 16; mm <<= 1) psum += __shfl_xor(psum, mm);
        lrow = lrow * corr + psum;
        mrow = mnew;
        #pragma unroll
        for (int u = 0; u < 24; u++) out[u] *= corr;
        ps[r][c*4+0]=p0; ps[r][c*4+1]=p1; ps[r][c*4+2]=p2; ps[r][c*4+3]=p3;
        // PV
        for (int d0 = 0; d0 < DD; d0 += 64) {
            __syncthreads();
            #pragma unroll
            for (int s = 0; s < 4; s++) {
                int i = t + s*256;
                int j = i >> 4, d4 = i & 15;
                float4 vv = (j < jmax) ? *(const float4*)(vb + (size_t)(j0+j)*DD + d0 + d4*4)
                                       : make_float4(0,0,0,0);
                *(float4*)&vs[j][d4*4] = vv;
            }
            __syncthreads();
            int ub = d0 >> 4;
            #pragma unroll 16
            for (int j = 0; j < 64; j++) {
                float pv = ps[r][j];
                out[ub+0] = fmaf(pv, vs[j][c+ 0], out[ub+0]);
                out[ub+1] = fmaf(pv, vs[j][c+16], out[ub+1]);
                out[ub+2] = fmaf(pv, vs[j][c+32], out[ub+2]);
                out[ub+3] = fmaf(pv, vs[j][c+48], out[ub+3]);
            }
        }
    }
    float inv = 1.f / lrow;
    int row = i0 + r;
    if (row < NSEQ) {
        float* xr = x + ((size_t)b*NSEQ + row)*DD;
        #pragma unroll
        for (int u = 0; u < 24; u++) {
            int d = (u >> 2)*64 + (u & 3)*16 + c;
            xr[d] += out[u] * inv;
        }
    }
}

// ---------------------------------------------------------------- head
__global__ __launch_bounds__(384) void head_kernel(const float* __restrict__ x,
    const float* __restrict__ g, const float* __restrict__ bb,
    const float* __restrict__ Wl1, const float* __restrict__ bl1,
    const float* __restrict__ Wl2, const float* __restrict__ bl2,
    float* __restrict__ outp) {
    __shared__ float yv[384];
    __shared__ float r1[6], r2[6], r3[6];
    int b = blockIdx.x, t = threadIdx.x;
    float v = x[(size_t)b*NSEQ*DD + t];
    float s = v;
    #pragma unroll
    for (int m = 1; m < 64; m <<= 1) s += __shfl_xor(s, m);
    if ((t & 63) == 0) r1[t>>6] = s;
    __syncthreads();
    float mu = (r1[0]+r1[1]+r1[2]+r1[3]+r1[4]+r1[5]) * (1.f/384.f);
    float dd = v - mu;
    float sq = dd*dd;
    #pragma unroll
    for (int m = 1; m < 64; m <<= 1) sq += __shfl_xor(sq, m);
    if ((t & 63) == 0) r2[t>>6] = sq;
    __syncthreads();
    float var = (r2[0]+r2[1]+r2[2]+r2[3]+r2[4]+r2[5]) * (1.f/384.f);
    float rstd = rsqrtf(var + 1e-5f);
    yv[t] = dd*rstd*g[t] + bb[t];
    __syncthreads();
    float acc = bl1[t];
    for (int d2 = 0; d2 < 384; d2++) acc = fmaf(yv[d2], Wl1[d2*384 + t], acc);
    acc = fmaxf(acc, 0.f);
    float o = acc * Wl2[t];
    #pragma unroll
    for (int m = 1; m < 64; m <<= 1) o += __shfl_xor(o, m);
    if ((t & 63) == 0) r3[t>>6] = o;
    __syncthreads();
    if (t == 0) outp[b] = r3[0]+r3[1]+r3[2]+r3[3]+r3[4]+r3[5] + bl2[0];
}

// ---------------------------------------------------------------- launch
extern "C" void kernel_launch(void* const* d_in, const int* in_sizes, int n_in,
                              void* d_out, int out_size, void* d_ws, size_t ws_size,
                              hipStream_t stream) {
    const float* search = (const float*)d_in[0];
    const float* target = (const float*)d_in[1];
    const float* cls    = (const float*)d_in[2];
    const float* spos   = (const float*)d_in[3];
    const float* tpos   = (const float*)d_in[4];
    const float* ln1_g  = (const float*)d_in[5];
    const float* ln1_b  = (const float*)d_in[6];
    const float* Wq     = (const float*)d_in[7];
    const float* bq     = (const float*)d_in[8];
    const float* Wk     = (const float*)d_in[9];
    const float* bk     = (const float*)d_in[10];
    const float* Wv     = (const float*)d_in[11];
    const float* bv     = (const float*)d_in[12];
    const float* ln2_g  = (const float*)d_in[13];
    const float* ln2_b  = (const float*)d_in[14];
    const float* W1     = (const float*)d_in[15];
    const float* b1     = (const float*)d_in[16];
    const float* W2     = (const float*)d_in[17];
    const float* b2     = (const float*)d_in[18];
    const float* lnf_g  = (const float*)d_in[19];
    const float* lnf_b  = (const float*)d_in[20];
    const float* Wl1    = (const float*)d_in[21];
    const float* bl1    = (const float*)d_in[22];
    const float* Wl2    = (const float*)d_in[23];
    const float* bl2    = (const float*)d_in[24];

    const size_t SZ = (size_t)NROWS * DD;       // 17,719,296 floats (70.9 MB)
    float* x     = (float*)d_ws;
    float* stats = x + SZ;
    float* qkv   = stats + (size_t)2*NROWS;

    // adaptive batch-chunk size: fit x + stats + 3*G*721*384 floats in ws_size
    const long per_b = 3L * NSEQ * DD;          // floats per batch for q,k,v
    long avail_f = (long)(ws_size / 4);
    long rem = avail_f - (long)SZ - 2L*NROWS;
    int G = (int)(rem / per_b);
    if (G > NBATCH) G = NBATCH;
    if (G < 1) G = 1;

    // build x
    {
        int total = NROWS * (DD/4);
        build_x_kernel<<<(total + 255)/256, 256, 0, stream>>>(search, target, cls, spos, tpos, x);
    }

    for (int l = 0; l < NLAYER; l++) {
        const float* wq = Wq + (size_t)l*DD*DD;
        const float* wk = Wk + (size_t)l*DD*DD;
        const float* wv = Wv + (size_t)l*DD*DD;
        const float* w1 = W1 + (size_t)l*DD*768;
        const float* w2 = W2 + (size_t)l*768*DD;
        for (int b0 = 0; b0 < NBATCH; b0 += G) {
            int cb = NBATCH - b0 < G ? NBATCH - b0 : G;
            int M  = cb * NSEQ;
            float* xc = x + (size_t)b0*NSEQ*DD;
            float* qc = qkv;
            float* kc = qkv + (size_t)M*DD;
            float* vc = qkv + (size_t)2*M*DD;
            float* mid = qkv;                   // M x 768, reuses q+k region
            dim3 g384(3, (M + 127)/128), g768(6, (M + 127)/128);
            int sblocks = (M + 3)/4;

            ln_stats_kernel<<<sblocks, 256, 0, stream>>>(xc, stats, M);
            gemm_f32<0,true><<<g384, 256, 0, stream>>>(xc, stats, ln1_g + l*DD, ln1_b + l*DD,
                                                       wq, bq + l*DD, nullptr, qc, M, DD, DD);
            gemm_f32<0,true><<<g384, 256, 0, stream>>>(xc, stats, ln1_g + l*DD, ln1_b + l*DD,
                                                       wk, bk + l*DD, nullptr, kc, M, DD, DD);
            gemm_f32<0,true><<<g384, 256, 0, stream>>>(xc, stats, ln1_g + l*DD, ln1_b + l*DD,
                                                       wv, bv + l*DD, nullptr, vc, M, DD, DD);
            attn_kernel<<<dim3(46, cb), 256, 0, stream>>>(qc, kc, vc, xc);
            ln_stats_kernel<<<sblocks, 256, 0, stream>>>(xc, stats, M);
            gemm_f32<1,true><<<g768, 256, 0, stream>>>(xc, stats, ln2_g + l*DD, ln2_b + l*DD,
                                                       w1, b1 + l*768, nullptr, mid, M, 768, DD);
            gemm_f32<2,false><<<g384, 256, 0, stream>>>(mid, nullptr, nullptr, nullptr,
                                                        w2, b2 + l*DD, xc, xc, M, DD, 768);
        }
    }
    head_kernel<<<NBATCH, 384, 0, stream>>>(x, lnf_g, lnf_b, Wl1, bl1, Wl2, bl2, (float*)d_out);
}

// Round 3
// 5166.921 us; speedup vs baseline: 3.2517x; 3.2517x over previous
//
#include <hip/hip_runtime.h>
#include <hip/hip_bf16.h>
#include <math.h>

#define DD 384
#define NBATCH 64
#define NSEQ 721
#define NROWS (NBATCH*NSEQ)   // 46144
#define NLAYER 4
#define VTW 736               // padded token width for transposed V

typedef __bf16 bf16_t;
typedef __bf16 bf16x8 __attribute__((ext_vector_type(8)));
typedef float  f32x4  __attribute__((ext_vector_type(4)));

static __device__ __forceinline__ void split_bf16(float v, bf16_t& h, bf16_t& l) {
    h = (bf16_t)v;
    l = (bf16_t)(v - (float)h);
}
static __device__ __forceinline__ bf16x8 bzero8() {
    bf16x8 v = {(bf16_t)0.f,(bf16_t)0.f,(bf16_t)0.f,(bf16_t)0.f,
                (bf16_t)0.f,(bf16_t)0.f,(bf16_t)0.f,(bf16_t)0.f};
    return v;
}

// ---------------------------------------------------------------- build x
__global__ void build_x_kernel(const float* __restrict__ search,
                               const float* __restrict__ target,
                               const float* __restrict__ cls,
                               const float* __restrict__ spos,
                               const float* __restrict__ tpos,
                               float* __restrict__ x) {
    int idx = blockIdx.x * blockDim.x + threadIdx.x;   // float4 index
    const int D4 = DD / 4;
    int total = NROWS * D4;
    if (idx >= total) return;
    int d4  = idx % D4;
    int row = idx / D4;
    int b = row / NSEQ;
    int n = row % NSEQ;
    float4 val;
    if (n == 0) {
        val = ((const float4*)cls)[d4];
    } else if (n <= 576) {
        int i = n - 1;
        float4 s = ((const float4*)search)[(size_t)(b*576 + i)*D4 + d4];
        float4 p = ((const float4*)spos)[(size_t)i*D4 + d4];
        val = make_float4(s.x+p.x, s.y+p.y, s.z+p.z, s.w+p.w);
    } else {
        int i = n - 577;
        float4 s = ((const float4*)target)[(size_t)(b*144 + i)*D4 + d4];
        float4 p = ((const float4*)tpos)[(size_t)i*D4 + d4];
        val = make_float4(s.x+p.x, s.y+p.y, s.z+p.z, s.w+p.w);
    }
    ((float4*)x)[idx] = val;
}

// ---------------------------------------------------------------- LN -> bf16 hi/lo
__global__ __launch_bounds__(256) void ln_bf16_kernel(const float* __restrict__ x,
                                                      const float* __restrict__ g,
                                                      const float* __restrict__ b,
                                                      bf16_t* __restrict__ yh,
                                                      bf16_t* __restrict__ yl,
                                                      int M) {
    int wave = threadIdx.x >> 6;
    int lane = threadIdx.x & 63;
    int row = blockIdx.x * 4 + wave;
    if (row >= M) return;
    const float* xr = x + (size_t)row * DD;
    float v[6];
    float s = 0.f;
    #pragma unroll
    for (int i = 0; i < 6; i++) { v[i] = xr[lane + 64*i]; s += v[i]; }
    #pragma unroll
    for (int m = 1; m < 64; m <<= 1) s += __shfl_xor(s, m);
    float mu = s * (1.f/DD);
    float vs = 0.f;
    #pragma unroll
    for (int i = 0; i < 6; i++) { float d = v[i]-mu; vs += d*d; }
    #pragma unroll
    for (int m = 1; m < 64; m <<= 1) vs += __shfl_xor(vs, m);
    float rstd = rsqrtf(vs * (1.f/DD) + 1e-5f);
    #pragma unroll
    for (int i = 0; i < 6; i++) {
        int d = lane + 64*i;
        float yv = (v[i]-mu)*rstd*g[d] + b[d];
        bf16_t hh, ll;
        split_bf16(yv, hh, ll);
        yh[(size_t)row*DD + d] = hh;
        yl[(size_t)row*DD + d] = ll;
    }
}

// ---------------------------------------------------------------- weight prep
// src [K][N] f32  ->  dst_h/dst_l [N][K] bf16 (transposed, hi/lo split)
__global__ void transpose_split_kernel(const float* __restrict__ src,
                                       bf16_t* __restrict__ dh,
                                       bf16_t* __restrict__ dl,
                                       int K, int N) {
    int idx = blockIdx.x * blockDim.x + threadIdx.x;
    if (idx >= K*N) return;
    int k = idx / N, n = idx % N;
    float v = src[idx];
    bf16_t h, l;
    split_bf16(v, h, l);
    dh[(size_t)n*K + k] = h;
    dl[(size_t)n*K + k] = l;
}

// zero the pad token columns (721..735) of transposed V
__global__ void zero_vt_pad_kernel(bf16_t* __restrict__ vh, bf16_t* __restrict__ vl, int cb) {
    int idx = blockIdx.x * blockDim.x + threadIdx.x;
    int total = cb * DD * 15;
    if (idx >= total) return;
    int j = idx % 15;
    int rem = idx / 15;                 // b_local*384 + d
    size_t o = (size_t)rem * VTW + NSEQ + j;
    vh[o] = (bf16_t)0.f;
    vl[o] = (bf16_t)0.f;
}

// ---------------------------------------------------------------- MFMA GEMM
// C[M,N] = epi( (Ah+Al)[M,K] @ (Bh+Bl)[K,N] + bias )
// A stored row-major [M][K] bf16 hi/lo; B stored TRANSPOSED [N][K] bf16 hi/lo.
// 3-pass split: AhBh + AhBl + AlBh.
// EPI 0: bf16-hi row-major out1
// EPI 1: hi/lo transposed-V out: out[(b*384+n)*736 + tok]
// EPI 2: exact gelu, hi/lo row-major out1/out2
// EPI 3: f32 out1 = val + res
template<int EPI>
__global__ __launch_bounds__(256, 2) void gemm_mfma(
        const bf16_t* __restrict__ ah, const bf16_t* __restrict__ al,
        const bf16_t* __restrict__ bh, const bf16_t* __restrict__ bl,
        const float* __restrict__ bias, const float* res,
        void* out1, void* out2,
        int M, int N, int K) {
    __shared__ bf16_t ls[32][64][8];   // 32 KB: [Ah 0..7 | Al 8..15 | Bh 16..23 | Bl 24..31]
    int t = threadIdx.x;
    int w = t >> 6, lane = t & 63;
    int c = lane & 15, g = lane >> 4;
    int wr = w >> 1, wc = w & 1;
    int m0 = blockIdx.y * 128, n0 = blockIdx.x * 128;

    // wave w stages region w (Ah/Al/Bh/Bl), frag f = round index
    const bf16_t* src0 = (w==0) ? ah : (w==1) ? al : (w==2) ? bh : bl;
    int base_rc = (w < 2) ? m0 : n0;

    f32x4 zero4 = {0.f,0.f,0.f,0.f};
    f32x4 acc[4][4];
    #pragma unroll
    for (int i = 0; i < 4; ++i)
        #pragma unroll
        for (int j = 0; j < 4; ++j) acc[i][j] = zero4;

    int ksteps = K >> 5;
    for (int kt = 0; kt < ksteps; ++kt) {
        int k0 = kt << 5;
        __syncthreads();
        #pragma unroll
        for (int i = 0; i < 8; ++i) {
            int rc = base_rc + 16*i + c;
            uint4 v = make_uint4(0,0,0,0);
            bool ok = (w >= 2) || (rc < M);
            if (ok) v = *(const uint4*)(src0 + (size_t)rc*K + k0 + 8*g);
            *(uint4*)&ls[w*8 + i][lane][0] = v;
        }
        __syncthreads();
        bf16x8 af_h[4], af_l[4], bf_h[4], bf_l[4];
        #pragma unroll
        for (int i = 0; i < 4; ++i) {
            af_h[i] = *(const bf16x8*)&ls[     4*wr + i][lane][0];
            af_l[i] = *(const bf16x8*)&ls[ 8 + 4*wr + i][lane][0];
            bf_h[i] = *(const bf16x8*)&ls[16 + 4*wc + i][lane][0];
            bf_l[i] = *(const bf16x8*)&ls[24 + 4*wc + i][lane][0];
        }
        #pragma unroll
        for (int i = 0; i < 4; ++i)
            #pragma unroll
            for (int j = 0; j < 4; ++j) {
                acc[i][j] = __builtin_amdgcn_mfma_f32_16x16x32_bf16(af_h[i], bf_h[j], acc[i][j], 0,0,0);
                acc[i][j] = __builtin_amdgcn_mfma_f32_16x16x32_bf16(af_h[i], bf_l[j], acc[i][j], 0,0,0);
                acc[i][j] = __builtin_amdgcn_mfma_f32_16x16x32_bf16(af_l[i], bf_h[j], acc[i][j], 0,0,0);
            }
    }

    // epilogue: D frag (i,j): row = m0+64wr+16i+4g+r, col = n0+64wc+16j+c
    #pragma unroll
    for (int j = 0; j < 4; ++j) {
        int n = n0 + 64*wc + 16*j + c;
        float bj = bias[n];
        #pragma unroll
        for (int i = 0; i < 4; ++i) {
            int rbase = m0 + 64*wr + 16*i + 4*g;
            #pragma unroll
            for (int r = 0; r < 4; ++r) {
                int row = rbase + r;
                if (row >= M) continue;
                float val = acc[i][j][r] + bj;
                if (EPI == 0) {
                    ((bf16_t*)out1)[(size_t)row*DD + n] = (bf16_t)val;
                } else if (EPI == 1) {
                    int bl_ = row / NSEQ;
                    int tok = row - bl_*NSEQ;
                    bf16_t h, l;
                    split_bf16(val, h, l);
                    size_t o = ((size_t)(bl_*DD + n))*VTW + tok;
                    ((bf16_t*)out1)[o] = h;
                    ((bf16_t*)out2)[o] = l;
                } else if (EPI == 2) {
                    val = 0.5f*val*(1.0f + erff(val*0.70710678118654752f));
                    bf16_t h, l;
                    split_bf16(val, h, l);
                    ((bf16_t*)out1)[(size_t)row*768 + n] = h;
                    ((bf16_t*)out2)[(size_t)row*768 + n] = l;
                } else {
                    float rv = res[(size_t)row*DD + n];
                    ((float*)out1)[(size_t)row*DD + n] = val + rv;
                }
            }
        }
    }
}

// ---------------------------------------------------------------- MFMA attention
// Block: 4 waves, 64 q-rows (wave w -> rows q0+16w+ (lane&15)).
// Per kv-tile (32): S^T = mfma(K, Q^T)  (S^T lane: q = lane&15, kv = 16mf+4g+r)
// online softmax per-lane; P lane-local as PV B-operand (pi(g,e) = 16(e>>2)+4g+(e&3)).
// PV: O^T = mfma(V^T, P^T): V^T read from LDS Vt[d][40] rows (V pre-transposed in global).
__global__ __launch_bounds__(256, 2) void attn_mfma(
        const bf16_t* __restrict__ qh, const bf16_t* __restrict__ kh,
        const bf16_t* __restrict__ vth, const bf16_t* __restrict__ vtl,
        float* __restrict__ x) {
    __shared__ __align__(16) char smem[61440];
    bf16_t* kf  = (bf16_t*)smem;            // [24 slots][64][8]  (24576 B) -- QK phase
    bf16_t* vhl = (bf16_t*)smem;            // [384][40]          (30720 B) -- PV phase
    bf16_t* vll = (bf16_t*)(smem + 30720);  // [384][40]

    int t = threadIdx.x, w = t >> 6, lane = t & 63;
    int c = lane & 15, g = lane >> 4;
    int bl_ = blockIdx.y;
    int q0 = blockIdx.x * 64;
    size_t bb = (size_t)bl_ * NSEQ;
    int qrow = q0 + 16*w + c;
    bool qok = (qrow < NSEQ);
    const float scale = 0.05103103630798287f;   // 384^-0.5

    bf16x8 qf[12];
    #pragma unroll
    for (int ks = 0; ks < 12; ++ks) {
        if (qok) qf[ks] = *(const bf16x8*)(qh + (bb + qrow)*DD + 32*ks + 8*g);
        else     qf[ks] = bzero8();
    }

    f32x4 zero4 = {0.f,0.f,0.f,0.f};
    f32x4 oacc[24];
    #pragma unroll
    for (int i = 0; i < 24; ++i) oacc[i] = zero4;
    float m_run = -1e30f, l_run = 0.f;

    for (int kt = 0; kt < 23; ++kt) {
        int kv0 = kt * 32;
        __syncthreads();                       // prev PV done (V region reused)
        // ---- stage K tile: 24 slots (ks, mf), frag-major
        #pragma unroll
        for (int i = 0; i < 6; ++i) {
            int s = i*4 + w;
            int ks = s >> 1, mf = s & 1;
            int kvrow = kv0 + 16*mf + c;
            uint4 v = make_uint4(0,0,0,0);
            if (kvrow < NSEQ) v = *(const uint4*)(kh + (bb + kvrow)*DD + 32*ks + 8*g);
            *(uint4*)(kf + ((size_t)s*64 + lane)*8) = v;
        }
        __syncthreads();
        // ---- S^T = K * Q^T
        f32x4 sacc[2];
        sacc[0] = zero4; sacc[1] = zero4;
        #pragma unroll
        for (int ks = 0; ks < 12; ++ks) {
            bf16x8 a0 = *(const bf16x8*)(kf + ((size_t)(2*ks+0)*64 + lane)*8);
            bf16x8 a1 = *(const bf16x8*)(kf + ((size_t)(2*ks+1)*64 + lane)*8);
            sacc[0] = __builtin_amdgcn_mfma_f32_16x16x32_bf16(a0, qf[ks], sacc[0], 0,0,0);
            sacc[1] = __builtin_amdgcn_mfma_f32_16x16x32_bf16(a1, qf[ks], sacc[1], 0,0,0);
        }
        // ---- online softmax (per q = c; kv = kv0 + 16mf + 4g + r)
        float p[2][4];
        float mx = -1e30f;
        #pragma unroll
        for (int mf = 0; mf < 2; ++mf)
            #pragma unroll
            for (int r = 0; r < 4; ++r) {
                float sv = sacc[mf][r] * scale;
                int kv = kv0 + 16*mf + 4*g + r;
                if (kv >= NSEQ) sv = -1e30f;
                p[mf][r] = sv;
                mx = fmaxf(mx, sv);
            }
        mx = fmaxf(mx, __shfl_xor(mx, 16));
        mx = fmaxf(mx, __shfl_xor(mx, 32));
        float m_new = fmaxf(m_run, mx);
        float corr = __expf(m_run - m_new);
        float psum = 0.f;
        #pragma unroll
        for (int mf = 0; mf < 2; ++mf)
            #pragma unroll
            for (int r = 0; r < 4; ++r) {
                float pv = __expf(p[mf][r] - m_new);
                p[mf][r] = pv;
                psum += pv;
            }
        psum += __shfl_xor(psum, 16);
        psum += __shfl_xor(psum, 32);
        l_run = l_run * corr + psum;
        m_run = m_new;
        #pragma unroll
        for (int i = 0; i < 24; ++i) oacc[i] *= corr;
        // ---- P fragments (lane-local): elem e=4mf+r  <->  kv = 16mf + 4g + r
        bf16x8 ph, pl;
        #pragma unroll
        for (int mf = 0; mf < 2; ++mf)
            #pragma unroll
            for (int r = 0; r < 4; ++r) {
                bf16_t hh, ll;
                split_bf16(p[mf][r], hh, ll);
                ph[mf*4 + r] = hh;
                pl[mf*4 + r] = ll;
            }
        __syncthreads();                       // all waves done reading K
        // ---- stage V tile (overwrites K region): Vt[d][40] hi/lo
        #pragma unroll
        for (int i = 0; i < 6; ++i) {
            int lin = i*256 + t;
            int d = lin >> 2, kv8 = lin & 3;
            size_t go = ((size_t)(bl_*DD + d))*VTW + kv0 + 8*kv8;
            uint4 v0 = *(const uint4*)(vth + go);
            uint4 v1 = *(const uint4*)(vtl + go);
            *(uint4*)(vhl + (size_t)d*40 + kv8*8) = v0;
            *(uint4*)(vll + (size_t)d*40 + kv8*8) = v1;
        }
        __syncthreads();
        // ---- O^T += V^T * P^T  (3-pass hi/lo)
        #pragma unroll
        for (int mf = 0; mf < 24; ++mf) {
            int dr = 16*mf + c;
            const bf16_t* vb  = vhl + (size_t)dr*40;
            const bf16_t* vb2 = vll + (size_t)dr*40;
            union { uint2 u[2]; bf16x8 v; } va, vc2;
            va.u[0]  = *(const uint2*)(vb  + 4*g);
            va.u[1]  = *(const uint2*)(vb  + 16 + 4*g);
            vc2.u[0] = *(const uint2*)(vb2 + 4*g);
            vc2.u[1] = *(const uint2*)(vb2 + 16 + 4*g);
            oacc[mf] = __builtin_amdgcn_mfma_f32_16x16x32_bf16(va.v,  ph, oacc[mf], 0,0,0);
            oacc[mf] = __builtin_amdgcn_mfma_f32_16x16x32_bf16(va.v,  pl, oacc[mf], 0,0,0);
            oacc[mf] = __builtin_amdgcn_mfma_f32_16x16x32_bf16(vc2.v, ph, oacc[mf], 0,0,0);
        }
    }
    // ---- epilogue: x[row][d] += O^T[d][q] / l
    float inv = 1.f / l_run;
    if (qok) {
        float* xr = x + (bb + qrow)*DD;
        #pragma unroll
        for (int mf = 0; mf < 24; ++mf)
            #pragma unroll
            for (int r = 0; r < 4; ++r) {
                int d = 16*mf + 4*g + r;
                xr[d] += oacc[mf][r] * inv;
            }
    }
}

// ---------------------------------------------------------------- head (f32)
__global__ __launch_bounds__(384) void head_kernel(const float* __restrict__ x,
    const float* __restrict__ g, const float* __restrict__ bb,
    const float* __restrict__ Wl1, const float* __restrict__ bl1,
    const float* __restrict__ Wl2, const float* __restrict__ bl2,
    float* __restrict__ outp) {
    __shared__ float yv[384];
    __shared__ float r1[6], r2[6], r3[6];
    int b = blockIdx.x, t = threadIdx.x;
    float v = x[(size_t)b*NSEQ*DD + t];
    float s = v;
    #pragma unroll
    for (int m = 1; m < 64; m <<= 1) s += __shfl_xor(s, m);
    if ((t & 63) == 0) r1[t>>6] = s;
    __syncthreads();
    float mu = (r1[0]+r1[1]+r1[2]+r1[3]+r1[4]+r1[5]) * (1.f/384.f);
    float dd = v - mu;
    float sq = dd*dd;
    #pragma unroll
    for (int m = 1; m < 64; m <<= 1) sq += __shfl_xor(sq, m);
    if ((t & 63) == 0) r2[t>>6] = sq;
    __syncthreads();
    float var = (r2[0]+r2[1]+r2[2]+r2[3]+r2[4]+r2[5]) * (1.f/384.f);
    float rstd = rsqrtf(var + 1e-5f);
    yv[t] = dd*rstd*g[t] + bb[t];
    __syncthreads();
    float acc = bl1[t];
    for (int d2 = 0; d2 < 384; d2++) acc = fmaf(yv[d2], Wl1[d2*384 + t], acc);
    acc = fmaxf(acc, 0.f);
    float o = acc * Wl2[t];
    #pragma unroll
    for (int m = 1; m < 64; m <<= 1) o += __shfl_xor(o, m);
    if ((t & 63) == 0) r3[t>>6] = o;
    __syncthreads();
    if (t == 0) outp[b] = r3[0]+r3[1]+r3[2]+r3[3]+r3[4]+r3[5] + bl2[0];
}

// ---------------------------------------------------------------- launch
extern "C" void kernel_launch(void* const* d_in, const int* in_sizes, int n_in,
                              void* d_out, int out_size, void* d_ws, size_t ws_size,
                              hipStream_t stream) {
    const float* search = (const float*)d_in[0];
    const float* target = (const float*)d_in[1];
    const float* cls    = (const float*)d_in[2];
    const float* spos   = (const float*)d_in[3];
    const float* tpos   = (const float*)d_in[4];
    const float* ln1_g  = (const float*)d_in[5];
    const float* ln1_b  = (const float*)d_in[6];
    const float* Wq     = (const float*)d_in[7];
    const float* bq     = (const float*)d_in[8];
    const float* Wk     = (const float*)d_in[9];
    const float* bk     = (const float*)d_in[10];
    const float* Wv     = (const float*)d_in[11];
    const float* bv     = (const float*)d_in[12];
    const float* ln2_g  = (const float*)d_in[13];
    const float* ln2_b  = (const float*)d_in[14];
    const float* W1     = (const float*)d_in[15];
    const float* b1     = (const float*)d_in[16];
    const float* W2     = (const float*)d_in[17];
    const float* b2     = (const float*)d_in[18];
    const float* lnf_g  = (const float*)d_in[19];
    const float* lnf_b  = (const float*)d_in[20];
    const float* Wl1    = (const float*)d_in[21];
    const float* bl1    = (const float*)d_in[22];
    const float* Wl2    = (const float*)d_in[23];
    const float* bl2    = (const float*)d_in[24];

    size_t off = 0;
    char* base = (char*)d_ws;
    auto alloc = [&](size_t bytes) -> void* {
        void* p = base + off;
        off += (bytes + 255) & ~(size_t)255;
        return p;
    };

    float* x = (float*)alloc((size_t)NROWS * DD * 4);            // 70.9 MB

    const int SQ = DD*DD;            // 147456
    const int SM = DD*768;           // 294912
    bf16_t* wqh = (bf16_t*)alloc((size_t)4*SQ*2);
    bf16_t* wql = (bf16_t*)alloc((size_t)4*SQ*2);
    bf16_t* wkh = (bf16_t*)alloc((size_t)4*SQ*2);
    bf16_t* wkl = (bf16_t*)alloc((size_t)4*SQ*2);
    bf16_t* wvh = (bf16_t*)alloc((size_t)4*SQ*2);
    bf16_t* wvl = (bf16_t*)alloc((size_t)4*SQ*2);
    bf16_t* w1h = (bf16_t*)alloc((size_t)4*SM*2);
    bf16_t* w1l = (bf16_t*)alloc((size_t)4*SM*2);
    bf16_t* w2h = (bf16_t*)alloc((size_t)4*SM*2);
    bf16_t* w2l = (bf16_t*)alloc((size_t)4*SM*2);

    // adaptive batch-chunk: per-batch chunk bytes (yh,yl,qh,kh + vth,vtl + midh,midl)
    const size_t perB = 4*(size_t)(NSEQ*DD*2) + 2*(size_t)(DD*VTW*2) + 2*(size_t)(NSEQ*768*2);
    size_t avail = (ws_size > off + 4096) ? (ws_size - off - 4096) : 0;
    int G = (int)(avail / perB);
    if (G > NBATCH) G = NBATCH;
    if (G < 1) G = 1;

    bf16_t* yh   = (bf16_t*)alloc((size_t)G*NSEQ*DD*2);
    bf16_t* yl   = (bf16_t*)alloc((size_t)G*NSEQ*DD*2);
    bf16_t* qhB  = (bf16_t*)alloc((size_t)G*NSEQ*DD*2);
    bf16_t* khB  = (bf16_t*)alloc((size_t)G*NSEQ*DD*2);
    bf16_t* vth  = (bf16_t*)alloc((size_t)G*DD*VTW*2);
    bf16_t* vtl  = (bf16_t*)alloc((size_t)G*DD*VTW*2);
    bf16_t* midh = (bf16_t*)alloc((size_t)G*NSEQ*768*2);
    bf16_t* midl = (bf16_t*)alloc((size_t)G*NSEQ*768*2);

    // build x
    build_x_kernel<<<(NROWS*(DD/4) + 255)/256, 256, 0, stream>>>(search, target, cls, spos, tpos, x);

    // weight prep (transpose + hi/lo split), all layers
    for (int l = 0; l < NLAYER; ++l) {
        transpose_split_kernel<<<(SQ+255)/256, 256, 0, stream>>>(Wq + (size_t)l*SQ, wqh + (size_t)l*SQ, wql + (size_t)l*SQ, DD, DD);
        transpose_split_kernel<<<(SQ+255)/256, 256, 0, stream>>>(Wk + (size_t)l*SQ, wkh + (size_t)l*SQ, wkl + (size_t)l*SQ, DD, DD);
        transpose_split_kernel<<<(SQ+255)/256, 256, 0, stream>>>(Wv + (size_t)l*SQ, wvh + (size_t)l*SQ, wvl + (size_t)l*SQ, DD, DD);
        transpose_split_kernel<<<(SM+255)/256, 256, 0, stream>>>(W1 + (size_t)l*SM, w1h + (size_t)l*SM, w1l + (size_t)l*SM, DD, 768);
        transpose_split_kernel<<<(SM+255)/256, 256, 0, stream>>>(W2 + (size_t)l*SM, w2h + (size_t)l*SM, w2l + (size_t)l*SM, 768, DD);
    }

    for (int l = 0; l < NLAYER; ++l) {
        for (int b0 = 0; b0 < NBATCH; b0 += G) {
            int cb = (NBATCH - b0 < G) ? (NBATCH - b0) : G;
            int Mc = cb * NSEQ;
            float* xc = x + (size_t)b0 * NSEQ * DD;
            dim3 gQKV(3, (Mc + 127)/128), gM1(6, (Mc + 127)/128), gM2(3, (Mc + 127)/128);

            ln_bf16_kernel<<<(Mc+3)/4, 256, 0, stream>>>(xc, ln1_g + l*DD, ln1_b + l*DD, yh, yl, Mc);
            zero_vt_pad_kernel<<<(cb*DD*15 + 255)/256, 256, 0, stream>>>(vth, vtl, cb);
            gemm_mfma<0><<<gQKV, 256, 0, stream>>>(yh, yl, wqh + (size_t)l*SQ, wql + (size_t)l*SQ,
                                                   bq + l*DD, nullptr, qhB, nullptr, Mc, DD, DD);
            gemm_mfma<0><<<gQKV, 256, 0, stream>>>(yh, yl, wkh + (size_t)l*SQ, wkl + (size_t)l*SQ,
                                                   bk + l*DD, nullptr, khB, nullptr, Mc, DD, DD);
            gemm_mfma<1><<<gQKV, 256, 0, stream>>>(yh, yl, wvh + (size_t)l*SQ, wvl + (size_t)l*SQ,
                                                   bv + l*DD, nullptr, vth, vtl, Mc, DD, DD);
            attn_mfma<<<dim3(12, cb), 256, 0, stream>>>(qhB, khB, vth, vtl, xc);
            ln_bf16_kernel<<<(Mc+3)/4, 256, 0, stream>>>(xc, ln2_g + l*DD, ln2_b + l*DD, yh, yl, Mc);
            gemm_mfma<2><<<gM1, 256, 0, stream>>>(yh, yl, w1h + (size_t)l*SM, w1l + (size_t)l*SM,
                                                  b1 + l*768, nullptr, midh, midl, Mc, 768, DD);
            gemm_mfma<3><<<gM2, 256, 0, stream>>>(midh, midl, w2h + (size_t)l*SM, w2l + (size_t)l*SM,
                                                  b2 + l*DD, xc, xc, nullptr, Mc, DD, 768);
        }
    }
    head_kernel<<<NBATCH, 384, 0, stream>>>(x, lnf_g, lnf_b, Wl1, bl1, Wl2, bl2, (float*)d_out);
}

// Round 4
// 4543.689 us; speedup vs baseline: 3.6978x; 1.1372x over previous
//
#include <hip/hip_runtime.h>
#include <hip/hip_bf16.h>
#include <math.h>

#define DD 384
#define NBATCH 64
#define NSEQ 721
#define NROWS (NBATCH*NSEQ)   // 46144
#define NLAYER 4
#define VTW 736               // padded token width for transposed V

typedef __bf16 bf16_t;
typedef __bf16 bf16x8 __attribute__((ext_vector_type(8)));
typedef float  f32x4  __attribute__((ext_vector_type(4)));

static __device__ __forceinline__ void split_bf16(float v, bf16_t& h, bf16_t& l) {
    h = (bf16_t)v;
    l = (bf16_t)(v - (float)h);
}
static __device__ __forceinline__ bf16x8 bzero8() {
    bf16x8 v = {(bf16_t)0.f,(bf16_t)0.f,(bf16_t)0.f,(bf16_t)0.f,
                (bf16_t)0.f,(bf16_t)0.f,(bf16_t)0.f,(bf16_t)0.f};
    return v;
}
// async global->LDS, 16B per lane; LDS dest is wave-uniform base + lane*16
static __device__ __forceinline__ void gload16(const void* g, void* l) {
    __builtin_amdgcn_global_load_lds(
        (const __attribute__((address_space(1))) unsigned int*)g,
        (__attribute__((address_space(3))) unsigned int*)l, 16, 0, 0);
}

// ---------------------------------------------------------------- build x
__global__ void build_x_kernel(const float* __restrict__ search,
                               const float* __restrict__ target,
                               const float* __restrict__ cls,
                               const float* __restrict__ spos,
                               const float* __restrict__ tpos,
                               float* __restrict__ x) {
    int idx = blockIdx.x * blockDim.x + threadIdx.x;   // float4 index
    const int D4 = DD / 4;
    int total = NROWS * D4;
    if (idx >= total) return;
    int d4  = idx % D4;
    int row = idx / D4;
    int b = row / NSEQ;
    int n = row % NSEQ;
    float4 val;
    if (n == 0) {
        val = ((const float4*)cls)[d4];
    } else if (n <= 576) {
        int i = n - 1;
        float4 s = ((const float4*)search)[(size_t)(b*576 + i)*D4 + d4];
        float4 p = ((const float4*)spos)[(size_t)i*D4 + d4];
        val = make_float4(s.x+p.x, s.y+p.y, s.z+p.z, s.w+p.w);
    } else {
        int i = n - 577;
        float4 s = ((const float4*)target)[(size_t)(b*144 + i)*D4 + d4];
        float4 p = ((const float4*)tpos)[(size_t)i*D4 + d4];
        val = make_float4(s.x+p.x, s.y+p.y, s.z+p.z, s.w+p.w);
    }
    ((float4*)x)[idx] = val;
}

// ---------------------------------------------------------------- LN -> bf16 hi/lo
__global__ __launch_bounds__(256) void ln_bf16_kernel(const float* __restrict__ x,
                                                      const float* __restrict__ g,
                                                      const float* __restrict__ b,
                                                      bf16_t* __restrict__ yh,
                                                      bf16_t* __restrict__ yl,
                                                      int M) {
    int wave = threadIdx.x >> 6;
    int lane = threadIdx.x & 63;
    int row = blockIdx.x * 4 + wave;
    if (row >= M) return;
    const float* xr = x + (size_t)row * DD;
    float v[6];
    float s = 0.f;
    #pragma unroll
    for (int i = 0; i < 6; i++) { v[i] = xr[lane + 64*i]; s += v[i]; }
    #pragma unroll
    for (int m = 1; m < 64; m <<= 1) s += __shfl_xor(s, m);
    float mu = s * (1.f/DD);
    float vs = 0.f;
    #pragma unroll
    for (int i = 0; i < 6; i++) { float d = v[i]-mu; vs += d*d; }
    #pragma unroll
    for (int m = 1; m < 64; m <<= 1) vs += __shfl_xor(vs, m);
    float rstd = rsqrtf(vs * (1.f/DD) + 1e-5f);
    #pragma unroll
    for (int i = 0; i < 6; i++) {
        int d = lane + 64*i;
        float yv = (v[i]-mu)*rstd*g[d] + b[d];
        bf16_t hh, ll;
        split_bf16(yv, hh, ll);
        yh[(size_t)row*DD + d] = hh;
        yl[(size_t)row*DD + d] = ll;
    }
}

// ---------------------------------------------------------------- weight prep
// src [K][N] f32  ->  dst_h/dst_l [N][K] bf16 (transposed, hi/lo split)
__global__ void transpose_split_kernel(const float* __restrict__ src,
                                       bf16_t* __restrict__ dh,
                                       bf16_t* __restrict__ dl,
                                       int K, int N) {
    int idx = blockIdx.x * blockDim.x + threadIdx.x;
    if (idx >= K*N) return;
    int k = idx / N, n = idx % N;
    float v = src[idx];
    bf16_t h, l;
    split_bf16(v, h, l);
    dh[(size_t)n*K + k] = h;
    dl[(size_t)n*K + k] = l;
}

// zero the pad token columns (721..735) of transposed V
__global__ void zero_vt_pad_kernel(bf16_t* __restrict__ vh, bf16_t* __restrict__ vl, int cb) {
    int idx = blockIdx.x * blockDim.x + threadIdx.x;
    int total = cb * DD * 15;
    if (idx >= total) return;
    int j = idx % 15;
    int rem = idx / 15;                 // b_local*384 + d
    size_t o = (size_t)rem * VTW + NSEQ + j;
    vh[o] = (bf16_t)0.f;
    vl[o] = (bf16_t)0.f;
}

// ---------------------------------------------------------------- GEMM core
// acc += (Ah+Al)[128 rows m0..][K] @ (Bh+Bl)^T rows n0.. ; A,B row-major [*][K].
// LDS [32 slots][64 lanes][8]: slots 0-7 Ah, 8-15 Al, 16-23 Bh, 24-31 Bl.
// Staging via global_load_lds (16B/lane, 1 KiB/slot). Tail rows (>=M) read
// garbage inside the ws guard; they only affect discarded output rows.
static __device__ __forceinline__ void gemm_core(
        const bf16_t* __restrict__ ah, const bf16_t* __restrict__ al,
        const bf16_t* __restrict__ bh, const bf16_t* __restrict__ bl,
        bf16_t (&ls)[32][64][8],
        int m0, int n0, int K, f32x4 (&acc)[4][4]) {
    int t = threadIdx.x;
    int w = t >> 6, lane = t & 63;
    int c = lane & 15, g = lane >> 4;
    int wr = w >> 1, wc = w & 1;
    const bf16_t* src0 = (w==0) ? ah : (w==1) ? al : (w==2) ? bh : bl;
    int base_rc = (w < 2) ? m0 : n0;
    const bf16_t* srcbase = src0 + (size_t)(base_rc + c)*K + 8*g;

    int ksteps = K >> 5;
    for (int kt = 0; kt < ksteps; ++kt) {
        int k0 = kt << 5;
        __syncthreads();                      // prev iter's frag reads done
        #pragma unroll
        for (int i = 0; i < 8; ++i)
            gload16(srcbase + (size_t)(16*i)*K + k0, &ls[w*8 + i][0][0]);
        __syncthreads();                      // DMA drained (vmcnt before barrier)
        bf16x8 af_h[4], af_l[4], bf_h[4], bf_l[4];
        #pragma unroll
        for (int i = 0; i < 4; ++i) {
            af_h[i] = *(const bf16x8*)&ls[     4*wr + i][lane][0];
            af_l[i] = *(const bf16x8*)&ls[ 8 + 4*wr + i][lane][0];
            bf_h[i] = *(const bf16x8*)&ls[16 + 4*wc + i][lane][0];
            bf_l[i] = *(const bf16x8*)&ls[24 + 4*wc + i][lane][0];
        }
        #pragma unroll
        for (int i = 0; i < 4; ++i)
            #pragma unroll
            for (int j = 0; j < 4; ++j) {
                acc[i][j] = __builtin_amdgcn_mfma_f32_16x16x32_bf16(af_h[i], bf_h[j], acc[i][j], 0,0,0);
                acc[i][j] = __builtin_amdgcn_mfma_f32_16x16x32_bf16(af_h[i], bf_l[j], acc[i][j], 0,0,0);
                acc[i][j] = __builtin_amdgcn_mfma_f32_16x16x32_bf16(af_l[i], bf_h[j], acc[i][j], 0,0,0);
            }
    }
}

// ---------------------------------------------------------------- fused QKV GEMM
// A [M][384] hi/lo; B packed [1152][384] hi/lo (rows 0-383 Wq^T, 384-767 Wk^T, 768-1151 Wv^T)
// seg by n0: Q/K -> bf16-hi row-major; V -> transposed hi/lo split [b*384+d][736]
__global__ __launch_bounds__(256, 2) void gemm_qkv(
        const bf16_t* __restrict__ ah, const bf16_t* __restrict__ al,
        const bf16_t* __restrict__ bh, const bf16_t* __restrict__ bl,
        const float* __restrict__ bq, const float* __restrict__ bk, const float* __restrict__ bv,
        bf16_t* __restrict__ qout, bf16_t* __restrict__ kout,
        bf16_t* __restrict__ vth, bf16_t* __restrict__ vtl,
        int M) {
    __shared__ __align__(16) bf16_t ls[32][64][8];
    int m0 = blockIdx.y * 128, n0 = blockIdx.x * 128;
    f32x4 zero4 = {0.f,0.f,0.f,0.f};
    f32x4 acc[4][4];
    #pragma unroll
    for (int i = 0; i < 4; ++i)
        #pragma unroll
        for (int j = 0; j < 4; ++j) acc[i][j] = zero4;
    gemm_core(ah, al, bh, bl, ls, m0, n0, DD, acc);

    int t = threadIdx.x, w = t >> 6, lane = t & 63;
    int c = lane & 15, g = lane >> 4;
    int wr = w >> 1, wc = w & 1;
    int seg = n0 / 384;                      // 0=Q 1=K 2=V (uniform: 384%128==0)
    const float* bias = (seg == 0) ? bq : (seg == 1) ? bk : bv;
    int segoff = seg * 384;
    #pragma unroll
    for (int j = 0; j < 4; ++j) {
        int nloc = n0 - segoff + 64*wc + 16*j + c;
        float bj = bias[nloc];
        #pragma unroll
        for (int i = 0; i < 4; ++i) {
            int rbase = m0 + 64*wr + 16*i + 4*g;
            #pragma unroll
            for (int r = 0; r < 4; ++r) {
                int row = rbase + r;
                if (row >= M) continue;
                float val = acc[i][j][r] + bj;
                if (seg == 0) {
                    qout[(size_t)row*DD + nloc] = (bf16_t)val;
                } else if (seg == 1) {
                    kout[(size_t)row*DD + nloc] = (bf16_t)val;
                } else {
                    int bl_ = row / NSEQ;
                    int tok = row - bl_*NSEQ;
                    bf16_t h, l;
                    split_bf16(val, h, l);
                    size_t o = ((size_t)(bl_*DD + nloc))*VTW + tok;
                    vth[o] = h;
                    vtl[o] = l;
                }
            }
        }
    }
}

// ---------------------------------------------------------------- MLP GEMMs
// EPI 2: exact gelu, hi/lo row-major [M][768]
// EPI 3: f32 out = val + res, [M][384]
template<int EPI>
__global__ __launch_bounds__(256, 2) void gemm_mfma(
        const bf16_t* __restrict__ ah, const bf16_t* __restrict__ al,
        const bf16_t* __restrict__ bh, const bf16_t* __restrict__ bl,
        const float* __restrict__ bias, const float* res,
        void* out1, void* out2,
        int M, int N, int K) {
    __shared__ __align__(16) bf16_t ls[32][64][8];
    int m0 = blockIdx.y * 128, n0 = blockIdx.x * 128;
    f32x4 zero4 = {0.f,0.f,0.f,0.f};
    f32x4 acc[4][4];
    #pragma unroll
    for (int i = 0; i < 4; ++i)
        #pragma unroll
        for (int j = 0; j < 4; ++j) acc[i][j] = zero4;
    gemm_core(ah, al, bh, bl, ls, m0, n0, K, acc);

    int t = threadIdx.x, w = t >> 6, lane = t & 63;
    int c = lane & 15, g = lane >> 4;
    int wr = w >> 1, wc = w & 1;
    #pragma unroll
    for (int j = 0; j < 4; ++j) {
        int n = n0 + 64*wc + 16*j + c;
        float bj = bias[n];
        #pragma unroll
        for (int i = 0; i < 4; ++i) {
            int rbase = m0 + 64*wr + 16*i + 4*g;
            #pragma unroll
            for (int r = 0; r < 4; ++r) {
                int row = rbase + r;
                if (row >= M) continue;
                float val = acc[i][j][r] + bj;
                if (EPI == 2) {
                    val = 0.5f*val*(1.0f + erff(val*0.70710678118654752f));
                    bf16_t h, l;
                    split_bf16(val, h, l);
                    ((bf16_t*)out1)[(size_t)row*768 + n] = h;
                    ((bf16_t*)out2)[(size_t)row*768 + n] = l;
                } else {
                    float rv = res[(size_t)row*DD + n];
                    ((float*)out1)[(size_t)row*DD + n] = val + rv;
                }
            }
        }
    }
}

// ---------------------------------------------------------------- MFMA attention
__global__ __launch_bounds__(256, 2) void attn_mfma(
        const bf16_t* __restrict__ qh, const bf16_t* __restrict__ kh,
        const bf16_t* __restrict__ vth, const bf16_t* __restrict__ vtl,
        float* __restrict__ x) {
    __shared__ __align__(16) char smem[61440];
    bf16_t* kf  = (bf16_t*)smem;            // [24 slots][64][8]  (24576 B) -- QK phase
    bf16_t* vhl = (bf16_t*)smem;            // [384][40]          (30720 B) -- PV phase
    bf16_t* vll = (bf16_t*)(smem + 30720);  // [384][40]

    int t = threadIdx.x, w = t >> 6, lane = t & 63;
    int c = lane & 15, g = lane >> 4;
    int bl_ = blockIdx.y;
    int q0 = blockIdx.x * 64;
    size_t bb = (size_t)bl_ * NSEQ;
    int qrow = q0 + 16*w + c;
    bool qok = (qrow < NSEQ);
    const float scale = 0.05103103630798287f;   // 384^-0.5

    bf16x8 qf[12];
    #pragma unroll
    for (int ks = 0; ks < 12; ++ks) {
        if (qok) qf[ks] = *(const bf16x8*)(qh + (bb + qrow)*DD + 32*ks + 8*g);
        else     qf[ks] = bzero8();
    }

    f32x4 zero4 = {0.f,0.f,0.f,0.f};
    f32x4 oacc[24];
    #pragma unroll
    for (int i = 0; i < 24; ++i) oacc[i] = zero4;
    float m_run = -1e30f, l_run = 0.f;

    for (int kt = 0; kt < 23; ++kt) {
        int kv0 = kt * 32;
        __syncthreads();                       // prev PV done (V region reused)
        #pragma unroll
        for (int i = 0; i < 6; ++i) {
            int s = i*4 + w;
            int ks = s >> 1, mf = s & 1;
            int kvrow = kv0 + 16*mf + c;
            uint4 v = make_uint4(0,0,0,0);
            if (kvrow < NSEQ) v = *(const uint4*)(kh + (bb + kvrow)*DD + 32*ks + 8*g);
            *(uint4*)(kf + ((size_t)s*64 + lane)*8) = v;
        }
        __syncthreads();
        f32x4 sacc[2];
        sacc[0] = zero4; sacc[1] = zero4;
        #pragma unroll
        for (int ks = 0; ks < 12; ++ks) {
            bf16x8 a0 = *(const bf16x8*)(kf + ((size_t)(2*ks+0)*64 + lane)*8);
            bf16x8 a1 = *(const bf16x8*)(kf + ((size_t)(2*ks+1)*64 + lane)*8);
            sacc[0] = __builtin_amdgcn_mfma_f32_16x16x32_bf16(a0, qf[ks], sacc[0], 0,0,0);
            sacc[1] = __builtin_amdgcn_mfma_f32_16x16x32_bf16(a1, qf[ks], sacc[1], 0,0,0);
        }
        float p[2][4];
        float mx = -1e30f;
        #pragma unroll
        for (int mf = 0; mf < 2; ++mf)
            #pragma unroll
            for (int r = 0; r < 4; ++r) {
                float sv = sacc[mf][r] * scale;
                int kv = kv0 + 16*mf + 4*g + r;
                if (kv >= NSEQ) sv = -1e30f;
                p[mf][r] = sv;
                mx = fmaxf(mx, sv);
            }
        mx = fmaxf(mx, __shfl_xor(mx, 16));
        mx = fmaxf(mx, __shfl_xor(mx, 32));
        float m_new = fmaxf(m_run, mx);
        float corr = __expf(m_run - m_new);
        float psum = 0.f;
        #pragma unroll
        for (int mf = 0; mf < 2; ++mf)
            #pragma unroll
            for (int r = 0; r < 4; ++r) {
                float pv = __expf(p[mf][r] - m_new);
                p[mf][r] = pv;
                psum += pv;
            }
        psum += __shfl_xor(psum, 16);
        psum += __shfl_xor(psum, 32);
        l_run = l_run * corr + psum;
        m_run = m_new;
        #pragma unroll
        for (int i = 0; i < 24; ++i) oacc[i] *= corr;
        bf16x8 ph, pl;
        #pragma unroll
        for (int mf = 0; mf < 2; ++mf)
            #pragma unroll
            for (int r = 0; r < 4; ++r) {
                bf16_t hh, ll;
                split_bf16(p[mf][r], hh, ll);
                ph[mf*4 + r] = hh;
                pl[mf*4 + r] = ll;
            }
        __syncthreads();                       // all waves done reading K
        #pragma unroll
        for (int i = 0; i < 6; ++i) {
            int lin = i*256 + t;
            int d = lin >> 2, kv8 = lin & 3;
            size_t go = ((size_t)(bl_*DD + d))*VTW + kv0 + 8*kv8;
            uint4 v0 = *(const uint4*)(vth + go);
            uint4 v1 = *(const uint4*)(vtl + go);
            *(uint4*)(vhl + (size_t)d*40 + kv8*8) = v0;
            *(uint4*)(vll + (size_t)d*40 + kv8*8) = v1;
        }
        __syncthreads();
        #pragma unroll
        for (int mf = 0; mf < 24; ++mf) {
            int dr = 16*mf + c;
            const bf16_t* vb  = vhl + (size_t)dr*40;
            const bf16_t* vb2 = vll + (size_t)dr*40;
            union { uint2 u[2]; bf16x8 v; } va, vc2;
            va.u[0]  = *(const uint2*)(vb  + 4*g);
            va.u[1]  = *(const uint2*)(vb  + 16 + 4*g);
            vc2.u[0] = *(const uint2*)(vb2 + 4*g);
            vc2.u[1] = *(const uint2*)(vb2 + 16 + 4*g);
            oacc[mf] = __builtin_amdgcn_mfma_f32_16x16x32_bf16(va.v,  ph, oacc[mf], 0,0,0);
            oacc[mf] = __builtin_amdgcn_mfma_f32_16x16x32_bf16(va.v,  pl, oacc[mf], 0,0,0);
            oacc[mf] = __builtin_amdgcn_mfma_f32_16x16x32_bf16(vc2.v, ph, oacc[mf], 0,0,0);
        }
    }
    float inv = 1.f / l_run;
    if (qok) {
        float* xr = x + (bb + qrow)*DD;
        #pragma unroll
        for (int mf = 0; mf < 24; ++mf)
            #pragma unroll
            for (int r = 0; r < 4; ++r) {
                int d = 16*mf + 4*g + r;
                xr[d] += oacc[mf][r] * inv;
            }
    }
}

// ---------------------------------------------------------------- head (f32)
__global__ __launch_bounds__(384) void head_kernel(const float* __restrict__ x,
    const float* __restrict__ g, const float* __restrict__ bb,
    const float* __restrict__ Wl1, const float* __restrict__ bl1,
    const float* __restrict__ Wl2, const float* __restrict__ bl2,
    float* __restrict__ outp) {
    __shared__ float yv[384];
    __shared__ float r1[6], r2[6], r3[6];
    int b = blockIdx.x, t = threadIdx.x;
    float v = x[(size_t)b*NSEQ*DD + t];
    float s = v;
    #pragma unroll
    for (int m = 1; m < 64; m <<= 1) s += __shfl_xor(s, m);
    if ((t & 63) == 0) r1[t>>6] = s;
    __syncthreads();
    float mu = (r1[0]+r1[1]+r1[2]+r1[3]+r1[4]+r1[5]) * (1.f/384.f);
    float dd = v - mu;
    float sq = dd*dd;
    #pragma unroll
    for (int m = 1; m < 64; m <<= 1) sq += __shfl_xor(sq, m);
    if ((t & 63) == 0) r2[t>>6] = sq;
    __syncthreads();
    float var = (r2[0]+r2[1]+r2[2]+r2[3]+r2[4]+r2[5]) * (1.f/384.f);
    float rstd = rsqrtf(var + 1e-5f);
    yv[t] = dd*rstd*g[t] + bb[t];
    __syncthreads();
    float acc = bl1[t];
    for (int d2 = 0; d2 < 384; d2++) acc = fmaf(yv[d2], Wl1[d2*384 + t], acc);
    acc = fmaxf(acc, 0.f);
    float o = acc * Wl2[t];
    #pragma unroll
    for (int m = 1; m < 64; m <<= 1) o += __shfl_xor(o, m);
    if ((t & 63) == 0) r3[t>>6] = o;
    __syncthreads();
    if (t == 0) outp[b] = r3[0]+r3[1]+r3[2]+r3[3]+r3[4]+r3[5] + bl2[0];
}

// ---------------------------------------------------------------- launch
extern "C" void kernel_launch(void* const* d_in, const int* in_sizes, int n_in,
                              void* d_out, int out_size, void* d_ws, size_t ws_size,
                              hipStream_t stream) {
    const float* search = (const float*)d_in[0];
    const float* target = (const float*)d_in[1];
    const float* cls    = (const float*)d_in[2];
    const float* spos   = (const float*)d_in[3];
    const float* tpos   = (const float*)d_in[4];
    const float* ln1_g  = (const float*)d_in[5];
    const float* ln1_b  = (const float*)d_in[6];
    const float* Wq     = (const float*)d_in[7];
    const float* bq     = (const float*)d_in[8];
    const float* Wk     = (const float*)d_in[9];
    const float* bk     = (const float*)d_in[10];
    const float* Wv     = (const float*)d_in[11];
    const float* bv     = (const float*)d_in[12];
    const float* ln2_g  = (const float*)d_in[13];
    const float* ln2_b  = (const float*)d_in[14];
    const float* W1     = (const float*)d_in[15];
    const float* b1     = (const float*)d_in[16];
    const float* W2     = (const float*)d_in[17];
    const float* b2     = (const float*)d_in[18];
    const float* lnf_g  = (const float*)d_in[19];
    const float* lnf_b  = (const float*)d_in[20];
    const float* Wl1    = (const float*)d_in[21];
    const float* bl1    = (const float*)d_in[22];
    const float* Wl2    = (const float*)d_in[23];
    const float* bl2    = (const float*)d_in[24];

    size_t off = 0;
    char* base = (char*)d_ws;
    auto alloc = [&](size_t bytes) -> void* {
        void* p = base + off;
        off += (bytes + 255) & ~(size_t)255;
        return p;
    };

    float* x = (float*)alloc((size_t)NROWS * DD * 4);            // 70.9 MB

    const int SQKV = 1152*DD;        // packed QKV weight rows
    const int SM = DD*768;           // 294912
    bf16_t* wqkvh = (bf16_t*)alloc((size_t)4*SQKV*2);
    bf16_t* wqkvl = (bf16_t*)alloc((size_t)4*SQKV*2);
    bf16_t* w1h = (bf16_t*)alloc((size_t)4*SM*2);
    bf16_t* w1l = (bf16_t*)alloc((size_t)4*SM*2);
    bf16_t* w2h = (bf16_t*)alloc((size_t)4*SM*2);
    bf16_t* w2l = (bf16_t*)alloc((size_t)4*SM*2);

    // adaptive batch-chunk; reserve 256KB for DMA tail-overread guard + slack
    const size_t perB = 4*(size_t)(NSEQ*DD*2) + 2*(size_t)(DD*VTW*2) + 2*(size_t)(NSEQ*768*2);
    size_t avail = (ws_size > off + 262144) ? (ws_size - off - 262144) : 0;
    int G = (int)(avail / perB);
    if (G > NBATCH) G = NBATCH;
    if (G < 1) G = 1;

    bf16_t* yh   = (bf16_t*)alloc((size_t)G*NSEQ*DD*2);
    bf16_t* yl   = (bf16_t*)alloc((size_t)G*NSEQ*DD*2);
    bf16_t* qhB  = (bf16_t*)alloc((size_t)G*NSEQ*DD*2);
    bf16_t* khB  = (bf16_t*)alloc((size_t)G*NSEQ*DD*2);
    bf16_t* vth  = (bf16_t*)alloc((size_t)G*DD*VTW*2);
    bf16_t* vtl  = (bf16_t*)alloc((size_t)G*DD*VTW*2);
    bf16_t* midh = (bf16_t*)alloc((size_t)G*NSEQ*768*2);
    bf16_t* midl = (bf16_t*)alloc((size_t)G*NSEQ*768*2);
    // guard region after last A-source buffer lives in the reserved 256KB

    build_x_kernel<<<(NROWS*(DD/4) + 255)/256, 256, 0, stream>>>(search, target, cls, spos, tpos, x);

    const int SQ = DD*DD;
    for (int l = 0; l < NLAYER; ++l) {
        bf16_t* dsth = wqkvh + (size_t)l*SQKV;
        bf16_t* dstl = wqkvl + (size_t)l*SQKV;
        transpose_split_kernel<<<(SQ+255)/256, 256, 0, stream>>>(Wq + (size_t)l*SQ, dsth,            dstl,            DD, DD);
        transpose_split_kernel<<<(SQ+255)/256, 256, 0, stream>>>(Wk + (size_t)l*SQ, dsth + 384*DD,   dstl + 384*DD,   DD, DD);
        transpose_split_kernel<<<(SQ+255)/256, 256, 0, stream>>>(Wv + (size_t)l*SQ, dsth + 768*DD,   dstl + 768*DD,   DD, DD);
        transpose_split_kernel<<<(SM+255)/256, 256, 0, stream>>>(W1 + (size_t)l*SM, w1h + (size_t)l*SM, w1l + (size_t)l*SM, DD, 768);
        transpose_split_kernel<<<(SM+255)/256, 256, 0, stream>>>(W2 + (size_t)l*SM, w2h + (size_t)l*SM, w2l + (size_t)l*SM, 768, DD);
    }

    for (int l = 0; l < NLAYER; ++l) {
        for (int b0 = 0; b0 < NBATCH; b0 += G) {
            int cb = (NBATCH - b0 < G) ? (NBATCH - b0) : G;
            int Mc = cb * NSEQ;
            float* xc = x + (size_t)b0 * NSEQ * DD;
            int mtiles = (Mc + 127)/128;

            ln_bf16_kernel<<<(Mc+3)/4, 256, 0, stream>>>(xc, ln1_g + l*DD, ln1_b + l*DD, yh, yl, Mc);
            zero_vt_pad_kernel<<<(cb*DD*15 + 255)/256, 256, 0, stream>>>(vth, vtl, cb);
            gemm_qkv<<<dim3(9, mtiles), 256, 0, stream>>>(yh, yl,
                    wqkvh + (size_t)l*SQKV, wqkvl + (size_t)l*SQKV,
                    bq + l*DD, bk + l*DD, bv + l*DD,
                    qhB, khB, vth, vtl, Mc);
            attn_mfma<<<dim3(12, cb), 256, 0, stream>>>(qhB, khB, vth, vtl, xc);
            ln_bf16_kernel<<<(Mc+3)/4, 256, 0, stream>>>(xc, ln2_g + l*DD, ln2_b + l*DD, yh, yl, Mc);
            gemm_mfma<2><<<dim3(6, mtiles), 256, 0, stream>>>(yh, yl,
                    w1h + (size_t)l*SM, w1l + (size_t)l*SM,
                    b1 + l*768, nullptr, midh, midl, Mc, 768, DD);
            gemm_mfma<3><<<dim3(3, mtiles), 256, 0, stream>>>(midh, midl,
                    w2h + (size_t)l*SM, w2l + (size_t)l*SM,
                    b2 + l*DD, xc, xc, nullptr, Mc, DD, 768);
        }
    }
    head_kernel<<<NBATCH, 384, 0, stream>>>(x, lnf_g, lnf_b, Wl1, bl1, Wl2, bl2, (float*)d_out);
}